// Round 11
// baseline (348.981 us; speedup 1.0000x reference)
//
#include <hip/hip_runtime.h>
#include <cmath>

#define TPB 256

typedef __attribute__((ext_vector_type(8)))  short short8;
typedef __attribute__((ext_vector_type(16))) float float16;

// ---- problem dims ----
static constexpr int  BB   = 16;
static constexpr int  TDIM = 2048;
static constexpr int  NN   = 24;
static constexpr int  P    = BB * NN;        // 384 (b,n) pairs
static constexpr int  C    = 64;
static constexpr int  TILE = 256;
static constexpr int  NBT  = TDIM / TILE;    // 8
static constexpr int  NSHARD = 64;
static constexpr float INV_CNT = 1.0f / 786432.0f;   // 1/(B*N*T)

// ---- ws byte offsets (all 256-aligned) ----
static constexpr size_t OFF_WEFF  = 6912;       // 576 f
static constexpr size_t OFF_WFRAG = 9216;       // 3*12288 bf16 (A-frag packed)
static constexpr size_t OFF_ST    = 82944;      // 4*8192 f (sharded stats)
static constexpr size_t OFF_BNAB  = 214016;     // 3*64 float2 (precomputed BN a,b)
static constexpr size_t OFF_O0    = 216320;     // 384*64*25 f
static constexpr size_t OFF_YT    = 2673920;    // 384*64*25 f
static constexpr size_t OFF_S     = 5131520;    // 3*384*2048 f
static constexpr size_t OFF_YA    = 14568704;   // 384*2048*64 bf16  [p][t][c]
static constexpr size_t OFF_YB    = 115232000;  // 384*2048*64 bf16  [p][t][c]

__device__ __forceinline__ unsigned short f2bf(float f) {
    unsigned int i = __float_as_uint(f);
    i += 0x7FFFu + ((i >> 16) & 1u);       // RNE
    return (unsigned short)(i >> 16);
}
__device__ __forceinline__ float bf2f(unsigned short u) {
    return __uint_as_float((unsigned)u << 16);
}
// pack 2 floats -> 2 bf16 in one u32 (round-half-up)
__device__ __forceinline__ unsigned pk2bf(float a, float b) {
    unsigned ua = __float_as_uint(a) + 0x8000u;
    unsigned ub = __float_as_uint(b) + 0x8000u;
    return __builtin_amdgcn_perm(ub, ua, 0x07060302u);
}
// XOR-swizzled Xl addressing: 260 rows x 8 cells x 8 bf16 (pad-free).
__device__ __forceinline__ int xidx(int tt, int ci) {
    return tt * 64 + (((ci ^ (tt & 7)) << 3));
}

// block-prologue: sharded stats -> per-channel BN (a,b) into abl[64].
__device__ __forceinline__
void bn_from_stats(const float* __restrict__ statsIn, const float* __restrict__ g,
                   const float* __restrict__ be, float2* abl, int tid)
{
    const int ch = tid >> 2, q = tid & 3;
    float s1 = 0.f, s2 = 0.f;
    #pragma unroll
    for (int u = 0; u < 4; ++u) {
        float4 a = *(const float4*)(statsIn + tid * 16 + u * 4);
        float4 b = *(const float4*)(statsIn + 4096 + tid * 16 + u * 4);
        s1 += a.x + a.y + a.z + a.w;
        s2 += b.x + b.y + b.z + b.w;
    }
    s1 += __shfl_xor(s1, 1); s1 += __shfl_xor(s1, 2);
    s2 += __shfl_xor(s2, 1); s2 += __shfl_xor(s2, 2);
    if (q == 0) {
        float mu  = s1 * INV_CNT;
        float var = s2 * INV_CNT - mu * mu;
        float a = g[ch] * (1.0f / sqrtf(var + 1e-5f));
        abl[ch] = make_float2(a, be[ch] - mu * a);
    }
}

// ---------------------------------------------------------------------------
// K0 (fused): blocks 0..143 pack conv weights into A-frag layout; block 144
// computes Weff + zeroes stats shards; blocks 145..528 compute s (each block
// builds its own Chebyshev row locally -> no cross-block dependency).
// ---------------------------------------------------------------------------
__global__ __launch_bounds__(TPB)
void prep_s_kernel(const float* __restrict__ adj, const float* __restrict__ theta,
                   const float* __restrict__ w1a,
                   const float* __restrict__ w1b, const float* __restrict__ w2a,
                   const float* __restrict__ w2b, const float* __restrict__ bx,
                   float* __restrict__ weff, unsigned short* __restrict__ wf,
                   float* __restrict__ stats, float* __restrict__ sbuf)
{
    __shared__ float bxs[256 * 25];
    __shared__ float disl[24];
    __shared__ float Ll[576];
    __shared__ float tkl[576];
    const int tid = threadIdx.x;
    const int blk = blockIdx.x;

    if (blk < 144) {
        int e = blk * TPB + tid;
        int conv = e / 12288, r = e % 12288;
        int oh = r / 6144; r %= 6144;
        int kc = r / 512;  r %= 512;
        int lane = r / 8;
        int jj = r % 8;
        int o = oh * 32 + (lane & 31);
        int K = kc * 16 + (lane >> 5) * 8 + jj;
        int j = K / 64, c2 = K % 64;
        const float* w = (conv == 0) ? w1b : ((conv == 1) ? w2a : w2b);
        wf[e] = f2bf(w[(o * 64 + c2) * 3 + j]);
        return;
    }
    if (blk == 144) {
        for (int e = tid; e < 4 * 8192; e += TPB) stats[e] = 0.f;
        for (int e = tid; e < 576; e += TPB) {
            int o = e / 9, k = (e % 9) / 3, j = e % 3;
            float a = 0.f;
            for (int c2 = 0; c2 < 64; ++c2)
                a += w1a[(o * 64 + c2) * 3 + j] * theta[k * 64 + c2];
            weff[(k * 3 + j) * 64 + o] = a;
        }
        return;
    }

    // ---- s compute: sblk = (b, k, tc)
    const int sblk = blk - 145;
    const int b  = sblk / 24;
    const int rr = sblk % 24;
    const int k  = rr >> 3;
    const int t0 = (rr & 7) * 256;

    if (tid < 24) {
        float d = 0.f;
        for (int j = 0; j < 24; ++j) d += adj[tid * 24 + j];
        disl[tid] = (d > 0.f) ? 1.0f / sqrtf(d) : 0.f;
    }
    for (int e = tid; e < 256 * 24; e += TPB) {
        int t = e / 24, m = e % 24;
        bxs[t * 25 + m] = bx[((long)b * TDIM + t0 + t) * NN + m];
    }
    __syncthreads();
    for (int e = tid; e < 576; e += TPB) {
        int i = e / 24, j = e % 24;
        Ll[e] = disl[i] * adj[j * 24 + i] * disl[j];
    }
    __syncthreads();
    if (k == 2) {
        for (int e = tid; e < 576; e += TPB) {
            int i = e / 24, j = e % 24;
            float a = 0.f;
            for (int m = 0; m < 24; ++m) a += Ll[i * 24 + m] * Ll[m * 24 + j];
            tkl[e] = 2.f * a - ((i == j) ? 1.f : 0.f);
        }
    } else {
        for (int e = tid; e < 576; e += TPB) {
            int i = e / 24, j = e % 24;
            tkl[e] = (k == 0) ? ((i == j) ? 1.f : 0.f) : Ll[e];
        }
    }
    __syncthreads();

    const int t = tid;
    float acc[24];
    if (k == 0) {
        #pragma unroll
        for (int n = 0; n < 24; ++n) acc[n] = bxs[t * 25 + n];
    } else {
        #pragma unroll
        for (int n = 0; n < 24; ++n) acc[n] = 0.f;
        for (int m = 0; m < 24; ++m) {
            float xb = bxs[t * 25 + m];
            const float* tr = tkl + m * 24;
            #pragma unroll
            for (int n = 0; n < 24; ++n) acc[n] = fmaf(xb, tr[n], acc[n]);
        }
    }
    for (int n = 0; n < 24; ++n)
        sbuf[((long)k * P + b * NN + n) * TDIM + t0 + t] = acc[n];
}

// ---------------------------------------------------------------------------
// bnprep: parallel reduce one sharded-stats slot -> per-channel (a,b).
// ---------------------------------------------------------------------------
__global__ __launch_bounds__(TPB)
void bnprep_kernel(const float* __restrict__ stats, const float* __restrict__ g,
                   const float* __restrict__ be, float2* __restrict__ ab)
{
    const int tid = threadIdx.x;
    const int ch = tid >> 2, q = tid & 3;
    float s1 = 0.f, s2 = 0.f;
    #pragma unroll
    for (int u = 0; u < 16; ++u) {
        int sh = q * 16 + u;
        s1 += stats[ch * 64 + sh];
        s2 += stats[(64 + ch) * 64 + sh];
    }
    s1 += __shfl_xor(s1, 1); s1 += __shfl_xor(s1, 2);
    s2 += __shfl_xor(s2, 1); s2 += __shfl_xor(s2, 2);
    if (q == 0) {
        float mu  = s1 * INV_CNT;
        float var = s2 * INV_CNT - mu * mu;
        float a = g[ch] * (1.0f / sqrtf(var + 1e-5f));
        ab[ch] = make_float2(a, be[ch] - mu * a);
    }
}

// ---------------------------------------------------------------------------
// K2: stats of y1a = Weff-conv(s) (bias-free; no store)
// ---------------------------------------------------------------------------
__global__ __launch_bounds__(TPB)
void stats1a_kernel(const float* __restrict__ sbuf, const float* __restrict__ weff,
                    float* __restrict__ statsOut)
{
    __shared__ float4 ssl4[3 * 66];
    __shared__ float4 wl4[144];
    __shared__ float  part[4][2][64];
    const int tid = threadIdx.x;
    const int blk = blockIdx.x;
    const int p  = blk >> 3;
    const int t0 = (blk & 7) * 256;

    for (int e = tid; e < 576; e += TPB) ((float*)wl4)[e] = weff[e];
    for (int e = tid; e < 3 * 65; e += TPB) {
        int k = e / 65, u4 = e % 65;
        int t = t0 - 4 + u4 * 4;
        float4 v = make_float4(0.f, 0.f, 0.f, 0.f);
        if (t >= 0) v = *(const float4*)(sbuf + ((long)k * P + p) * TDIM + t);
        ssl4[k * 66 + u4] = v;
    }
    __syncthreads();

    const int oq = tid & 7;
    const int tq = tid >> 3;
    float acc[8][8];
    #pragma unroll
    for (int i = 0; i < 8; ++i)
        #pragma unroll
        for (int ti = 0; ti < 8; ++ti) acc[i][ti] = 0.f;

    #pragma unroll
    for (int k = 0; k < 3; ++k) {
        float4 x0 = ssl4[k * 66 + tq * 2];
        float4 x1 = ssl4[k * 66 + tq * 2 + 1];
        float4 x2 = ssl4[k * 66 + tq * 2 + 2];
        float xv[12] = { x0.x,x0.y,x0.z,x0.w, x1.x,x1.y,x1.z,x1.w, x2.x,x2.y,x2.z,x2.w };
        #pragma unroll
        for (int j = 0; j < 3; ++j) {
            float4 w0 = wl4[(k * 3 + j) * 16 + oq * 2];
            float4 w1 = wl4[(k * 3 + j) * 16 + oq * 2 + 1];
            float wv[8] = { w0.x,w0.y,w0.z,w0.w, w1.x,w1.y,w1.z,w1.w };
            #pragma unroll
            for (int i = 0; i < 8; ++i)
                #pragma unroll
                for (int ti = 0; ti < 8; ++ti)
                    acc[i][ti] = fmaf(wv[i], xv[ti + 2 + j], acc[i][ti]);
        }
    }

    float s1v[8], s2v[8];
    #pragma unroll
    for (int i = 0; i < 8; ++i) {
        float a1 = 0.f, a2 = 0.f;
        #pragma unroll
        for (int ti = 0; ti < 8; ++ti) { a1 += acc[i][ti]; a2 += acc[i][ti] * acc[i][ti]; }
        s1v[i] = a1; s2v[i] = a2;
    }
    #pragma unroll
    for (int m = 8; m < 64; m <<= 1) {
        #pragma unroll
        for (int i = 0; i < 8; ++i) {
            s1v[i] += __shfl_xor(s1v[i], m);
            s2v[i] += __shfl_xor(s2v[i], m);
        }
    }
    const int wave = tid >> 6, lane = tid & 63;
    if (lane < 8) {
        #pragma unroll
        for (int i = 0; i < 8; ++i) {
            part[wave][0][oq * 8 + i] = s1v[i];
            part[wave][1][oq * 8 + i] = s2v[i];
        }
    }
    __syncthreads();
    if (tid < 128) {
        int s = tid >> 6, o = tid & 63;
        float tot = part[0][s][o] + part[1][s][o] + part[2][s][o] + part[3][s][o];
        atomicAdd(&statsOut[(s * 64 + o) * NSHARD + (blk & 63)], tot);
    }
}

// ---------------------------------------------------------------------------
// MFMA conv pass — R10 structure (swizzled Xl, scratch overlay, 4 blocks/CU)
// + register-hoisted BN/theta coefficients + acc-based stats in ALL modes
// (store loop = pure copy). 256-t tiles, K = j*64+c, y bf16 [p][t][c].
// MODE 0: conv1b — xin from s (Weff conv + BN1a + relu), dil 1.
// MODE 1: conv2a — xin = relu(relu(BN1b(yin)) + gc), dil 2; fp32 out0 tail.
// MODE 2: conv2b — xin = relu(BN2a(yin)), dil 2; fp32 last-25 tail only.
// ---------------------------------------------------------------------------
template<int MODE>
__global__ __launch_bounds__(TPB, 4)
void conv_mfma(const float* __restrict__ sbuf, const unsigned short* __restrict__ yin,
               unsigned short* __restrict__ yout, float* __restrict__ ytail,
               const unsigned short* __restrict__ wf, const float* __restrict__ weff,
               const float2* __restrict__ bnab, float* __restrict__ statsOut,
               const float* __restrict__ theta, float* __restrict__ o0s)
{
    constexpr int SCR = (MODE == 0) ? (792 + 576) : ((MODE == 1) ? (792 + 192) : 256);
    __shared__ unsigned short Xl[260 * 64];   // 33.25 KB, XOR-swizzled cells
    __shared__ float  scratch[SCR];           // staging: ssl(+weffl/thl); end: parts
    __shared__ float2 abl[64];

    float* const ssl   = scratch;             // [3][264] (MODE<=1), staging only
    float* const weffl = scratch + 792;       // MODE 0
    float* const thl   = scratch + 792;       // MODE 1
    float* const parts = scratch;             // reused after staging completes

    const int tid  = threadIdx.x;
    const int lane = tid & 63;
    const int w    = tid >> 6;
    const int oh   = w & 1;
    const int l31  = lane & 31;
    const int h    = lane >> 5;
    const int cb   = tid & 7;                 // channel-block, constant/thread
    const int blk  = blockIdx.x;
    const int p    = blk >> 3;
    const int tile = blk & 7;
    const int t0   = tile * TILE;

    // A-fragments (weights), resident
    short8 af[12];
    #pragma unroll
    for (int kc = 0; kc < 12; ++kc)
        af[kc] = *((const short8*)wf + (oh * 12 + kc) * 64 + lane);

    if (tid < 64) abl[tid] = bnab[tid];       // precomputed BN (a,b)
    if (MODE == 0)
        for (int e = tid; e < 576; e += TPB) weffl[e] = weff[e];
    if (MODE == 1)
        if (tid < 192) thl[tid] = theta[tid];
    if (MODE <= 1) {
        // s halo 8: ssl[k][it] = s[k][t0-8+it], it in 0..263
        for (int e = tid; e < 3 * 66; e += TPB) {
            int k = e / 66, u4 = e % 66;
            int t = t0 - 8 + u4 * 4;
            float4 v = make_float4(0.f, 0.f, 0.f, 0.f);
            if (t >= 0) v = *(const float4*)(sbuf + ((long)k * P + p) * TDIM + t);
            *(float4*)(ssl + k * 264 + u4 * 4) = v;
        }
    }
    __syncthreads();

    // register-hoisted per-thread coefficients (cb fixed -> 8 channels)
    float2 ab2[8];
    #pragma unroll
    for (int r = 0; r < 8; ++r) ab2[r] = abl[cb * 8 + r];
    float th2[3][8];
    if (MODE == 1) {
        #pragma unroll
        for (int k = 0; k < 3; ++k)
            #pragma unroll
            for (int r = 0; r < 8; ++r) th2[k][r] = thl[k * 64 + cb * 8 + r];
    }

    // ---- stage X transposed [t][c] (swizzled): tasks (tt 0..259, cb fixed)
    const unsigned short* yinb = (MODE >= 1)
        ? (yin + ((long)p * TDIM + t0 - 4) * 64) : nullptr;
    for (int e = tid; e < 260 * 8; e += TPB) {
        const int tt = e >> 3;
        const int t = t0 - 4 + tt;
        float xv[8];
        if (t < 0) {
            #pragma unroll
            for (int r = 0; r < 8; ++r) xv[r] = 0.f;   // causal zero pad
        } else if (MODE == 0) {
            float sv[9];
            #pragma unroll
            for (int k = 0; k < 3; ++k)
                #pragma unroll
                for (int j = 0; j < 3; ++j)
                    sv[k * 3 + j] = ssl[k * 264 + tt + 2 + j];
            #pragma unroll
            for (int r = 0; r < 8; ++r) {
                int c = cb * 8 + r;
                float raw = 0.f;
                #pragma unroll
                for (int u = 0; u < 9; ++u)
                    raw = fmaf(weffl[u * 64 + c], sv[u], raw);
                xv[r] = fmaxf(fmaf(ab2[r].x, raw, ab2[r].y), 0.f);
            }
        } else {
            short8 yv8 = *(const short8*)(yinb + (long)e * 8);
            float gcb[3];
            if (MODE == 1) {
                gcb[0] = ssl[      tt + 4];
                gcb[1] = ssl[264 + tt + 4];
                gcb[2] = ssl[528 + tt + 4];
            }
            #pragma unroll
            for (int r = 0; r < 8; ++r) {
                float v = bf2f((unsigned short)yv8[r]);
                float hh = fmaxf(fmaf(ab2[r].x, v, ab2[r].y), 0.f);
                if (MODE == 1) {
                    float gc = th2[0][r] * gcb[0] + th2[1][r] * gcb[1] + th2[2][r] * gcb[2];
                    hh = fmaxf(hh + gc, 0.f);
                }
                xv[r] = hh;
            }
        }
        if (MODE == 1 && tile == 7 && tt >= 235) {
            #pragma unroll
            for (int r = 0; r < 8; ++r)
                o0s[(long)p * 1600 + (cb * 8 + r) * 25 + (tt - 235)] = xv[r];
        }
        uint4 pk;
        pk.x = pk2bf(xv[0], xv[1]);
        pk.y = pk2bf(xv[2], xv[3]);
        pk.z = pk2bf(xv[4], xv[5]);
        pk.w = pk2bf(xv[6], xv[7]);
        *(uint4*)(Xl + xidx(tt, cb)) = pk;
    }
    __syncthreads();

    // ---- MFMA: wave w -> o-half oh, t-tiles (w>>1)*4 .. +3
    float16 acc[4];
    #pragma unroll
    for (int i = 0; i < 4; ++i)
        #pragma unroll
        for (int r = 0; r < 16; ++r) acc[i][r] = 0.f;

    const int tqb = (w >> 1) * 4;
    #pragma unroll
    for (int kc = 0; kc < 12; ++kc) {
        const int j = kc >> 2;
        const int roff = (MODE == 0) ? (2 + j) : (2 * j);   // dil 1 / dil 2
        const int ci = (kc & 3) * 2 + h;                    // 16-B cell index
        #pragma unroll
        for (int i = 0; i < 4; ++i) {
            int row = (tqb + i) * 32 + l31 + roff;
            short8 bfr = *(const short8*)(Xl + xidx(row, ci));
            acc[i] = __builtin_amdgcn_mfma_f32_32x32x16_bf16(af[kc], bfr, acc[i], 0, 0, 0);
        }
    }

    // ---- stats from fp32 accumulators (all modes; R3/R4-proven numerics)
    {
        float s1[16], s2[16];
        #pragma unroll
        for (int r = 0; r < 16; ++r) {
            float a1 = 0.f, a2 = 0.f;
            #pragma unroll
            for (int i = 0; i < 4; ++i) { float v = acc[i][r]; a1 += v; a2 = fmaf(v, v, a2); }
            s1[r] = a1; s2[r] = a2;
        }
        #pragma unroll
        for (int m = 1; m <= 16; m <<= 1) {
            #pragma unroll
            for (int r = 0; r < 16; ++r) {
                s1[r] += __shfl_xor(s1[r], m);
                s2[r] += __shfl_xor(s2[r], m);
            }
        }
        if (l31 == 0) {
            float* pw = parts + (w * 2 + h) * 32;           // max idx 255 < SCR
            #pragma unroll
            for (int r = 0; r < 16; ++r) { pw[r * 2] = s1[r]; pw[r * 2 + 1] = s2[r]; }
        }
    }

    if (MODE <= 1) {
        __syncthreads();   // Xl B-frag reads done; parts (scratch) visible

        // ---- epilogue: acc -> Xl (bf16, [t][c], swizzled)
        #pragma unroll
        for (int i = 0; i < 4; ++i) {
            int tl = (tqb + i) * 32 + l31;
            #pragma unroll
            for (int qq = 0; qq < 4; ++qq) {
                int ci = oh * 4 + qq;
                uint2 pk;
                pk.x = pk2bf(acc[i][4 * qq + 0], acc[i][4 * qq + 1]);
                pk.y = pk2bf(acc[i][4 * qq + 2], acc[i][4 * qq + 3]);
                *(uint2*)(Xl + xidx(tl, ci) + 4 * h) = pk;
            }
        }
        __syncthreads();

        // ---- pure-copy coalesced global store
        unsigned short* youtb = yout + ((long)p * TDIM + t0) * 64;
        #pragma unroll
        for (int it = 0; it < 8; ++it) {
            int e = tid + it * 256;
            int tt = e >> 3;
            uint4 v = *(const uint4*)(Xl + xidx(tt, cb));
            *(uint4*)(youtb + (long)e * 8) = v;
        }
    } else {
        // ---- MODE 2: fp32 tail store straight from accumulators
        if (tile == 7) {
            #pragma unroll
            for (int i = 0; i < 4; ++i) {
                int tg = t0 + (tqb + i) * 32 + l31;
                if (tg >= TDIM - 25) {
                    #pragma unroll
                    for (int r = 0; r < 16; ++r) {
                        int o = oh * 32 + (r & 3) + 8 * (r >> 2) + 4 * h;
                        ytail[((long)p * C + o) * 25 + (tg - (TDIM - 25))] = acc[i][r];
                    }
                }
            }
        }
        __syncthreads();   // parts visible
    }

    // ---- final stats reduce + sharded atomics (same mapping all modes)
    if (tid < 64) {
        int o = tid;
        int ohh = o >> 5, v = o & 31;
        int hh = (v >> 2) & 1, r = (v & 3) + 4 * (v >> 3);
        float t1 = parts[(ohh * 2 + hh) * 32 + r * 2]
                 + parts[((ohh + 2) * 2 + hh) * 32 + r * 2];
        float t2 = parts[(ohh * 2 + hh) * 32 + r * 2 + 1]
                 + parts[((ohh + 2) * 2 + hh) * 32 + r * 2 + 1];
        atomicAdd(&statsOut[o * NSHARD + (blk & 63)], t1);
        atomicAdd(&statsOut[(64 + o) * NSHARD + (blk & 63)], t2);
    }
}

// ---------------------------------------------------------------------------
// K6: head. BN2b (a,b) computed in-block from shards; out = relu(bn2b(ytail))
// + out0 ; 1x1 conv -> relu ; (1,2) conv ; slice last 24 t ; transpose.
// ---------------------------------------------------------------------------
__global__ __launch_bounds__(TPB)
void end_kernel(const float* __restrict__ ytail, const float* __restrict__ o0s,
                const float* __restrict__ statsIn, const float* __restrict__ g,
                const float* __restrict__ be, const float* __restrict__ w_end,
                const float* __restrict__ b_end, const float* __restrict__ w_end1,
                const float* __restrict__ b_end1, float* __restrict__ out)
{
    __shared__ float2 abl[64];
    __shared__ float outl[64 * 25];
    __shared__ float e1l[32 * 25];
    __shared__ float wendl[2048];
    const int tid = threadIdx.x;
    const int p = blockIdx.x;
    const int b = p / 24, n = p % 24;

    bn_from_stats(statsIn, g, be, abl, tid);
    for (int e = tid; e < 2048; e += TPB) wendl[e] = w_end[e];
    __syncthreads();

    for (int e = tid; e < 1600; e += TPB) {
        int c = e / 25, tau = e % 25;
        float v = ytail[((long)p * C + c) * 25 + tau];
        float2 ab = abl[c];
        outl[e] = fmaxf(ab.x * v + ab.y, 0.f) + o0s[(long)p * 1600 + e];
    }
    __syncthreads();
    for (int e = tid; e < 800; e += TPB) {
        int q = e / 25, tau = e % 25;
        float a = b_end[q];
        for (int c = 0; c < 64; ++c)
            a = fmaf(wendl[q * 64 + c], outl[c * 25 + tau], a);
        e1l[e] = fmaxf(a, 0.f);
    }
    __syncthreads();
    if (tid < 24) {
        float a = b_end1[0];
        #pragma unroll
        for (int q = 0; q < 32; ++q)
            a += w_end1[q * 2] * e1l[q * 25 + tid] + w_end1[q * 2 + 1] * e1l[q * 25 + tid + 1];
        out[((long)b * 24 + tid) * 24 + n] = a;
    }
}

// ---------------------------------------------------------------------------
extern "C" void kernel_launch(void* const* d_in, const int* in_sizes, int n_in,
                              void* d_out, int out_size, void* d_ws, size_t ws_size,
                              hipStream_t stream)
{
    (void)in_sizes; (void)n_in; (void)out_size; (void)ws_size;
    const float* bx    = (const float*)d_in[0];
    const float* adj   = (const float*)d_in[1];
    const float* theta = (const float*)d_in[2];
    const float* w1a   = (const float*)d_in[3];
    const float* g1a   = (const float*)d_in[5];
    const float* be1a  = (const float*)d_in[6];
    const float* w1b   = (const float*)d_in[7];
    const float* g1b   = (const float*)d_in[9];
    const float* be1b  = (const float*)d_in[10];
    const float* w2a   = (const float*)d_in[11];
    const float* g2a   = (const float*)d_in[13];
    const float* be2a  = (const float*)d_in[14];
    const float* w2b   = (const float*)d_in[15];
    const float* g2b   = (const float*)d_in[17];
    const float* be2b  = (const float*)d_in[18];
    const float* wend  = (const float*)d_in[19];
    const float* bend  = (const float*)d_in[20];
    const float* wend1 = (const float*)d_in[21];
    const float* bend1 = (const float*)d_in[22];

    char* ws = (char*)d_ws;
    float*          weff  = (float*)(ws + OFF_WEFF);
    unsigned short* wf    = (unsigned short*)(ws + OFF_WFRAG);
    float*          stats = (float*)(ws + OFF_ST);
    float2*         bnab  = (float2*)(ws + OFF_BNAB);
    float*          o0s   = (float*)(ws + OFF_O0);
    float*          ytail = (float*)(ws + OFF_YT);
    float*          sb    = (float*)(ws + OFF_S);
    unsigned short* yA    = (unsigned short*)(ws + OFF_YA);
    unsigned short* yB    = (unsigned short*)(ws + OFF_YB);

    prep_s_kernel <<<145 + 384, TPB, 0, stream>>>(adj, theta, w1a, w1b, w2a, w2b,
                                                  bx, weff, wf, stats, sb);
    stats1a_kernel<<<P * NBT, TPB, 0, stream>>>(sb, weff, stats);
    bnprep_kernel <<<1, TPB, 0, stream>>>(stats,         g1a, be1a, bnab);

    // conv1b: s -> yA, BN1a consumer-side, stats -> slot1
    conv_mfma<0><<<P * NBT, TPB, 0, stream>>>(
        sb, nullptr, yA, nullptr, wf, weff,
        bnab, stats + 8192, nullptr, nullptr);
    bnprep_kernel <<<1, TPB, 0, stream>>>(stats + 8192,  g1b, be1b, bnab + 64);

    // conv2a: yA -> yB, BN1b + gc residual, stats -> slot2, fp32 out0 tail
    conv_mfma<1><<<P * NBT, TPB, 0, stream>>>(
        sb, yA, yB, nullptr, wf + 12288, nullptr,
        bnab + 64, stats + 16384, theta, o0s);
    bnprep_kernel <<<1, TPB, 0, stream>>>(stats + 16384, g2a, be2a, bnab + 128);

    // conv2b: yB -> ytail (fp32 last-25), BN2a, stats -> slot3
    conv_mfma<2><<<P * NBT, TPB, 0, stream>>>(
        sb, yB, nullptr, ytail, wf + 24576, nullptr,
        bnab + 128, stats + 24576, nullptr, nullptr);

    // head: BN2b in-block from slot3 shards
    end_kernel<<<P, TPB, 0, stream>>>(ytail, o0s, stats + 24576, g2b, be2b,
                                      wend, bend, wend1, bend1, (float*)d_out);
}

// Round 12
// 331.311 us; speedup vs baseline: 1.0533x; 1.0533x over previous
//
#include <hip/hip_runtime.h>
#include <cmath>

#define TPB 256

typedef __attribute__((ext_vector_type(8)))  short short8;
typedef __attribute__((ext_vector_type(16))) float float16;

// ---- problem dims ----
static constexpr int  BB   = 16;
static constexpr int  TDIM = 2048;
static constexpr int  NN   = 24;
static constexpr int  P    = BB * NN;        // 384 (b,n) pairs
static constexpr int  C    = 64;
static constexpr int  TILE = 256;
static constexpr int  NBT  = TDIM / TILE;    // 8
static constexpr int  NSHARD = 64;
static constexpr float INV_CNT = 1.0f / 786432.0f;   // 1/(B*N*T)

// ---- ws byte offsets (all 256-aligned) ----
static constexpr size_t OFF_TK    = 0;          // 1728 f
static constexpr size_t OFF_WEFF  = 6912;       // 576 f
static constexpr size_t OFF_WFRAG = 9216;       // 3*12288 bf16 (A-frag packed)
static constexpr size_t OFF_ST    = 82944;      // 4*8192 f (sharded stats)
static constexpr size_t OFF_BNAB  = 214016;     // 4*64 float2 (precomputed BN a,b)
static constexpr size_t OFF_O0    = 216320;     // 384*64*25 f
static constexpr size_t OFF_YT    = 2673920;    // 384*64*25 f
static constexpr size_t OFF_S     = 5131520;    // 3*384*2048 f
static constexpr size_t OFF_YA    = 14568704;   // 384*2048*64 bf16  [p][t][c]
static constexpr size_t OFF_YB    = 115232000;  // 384*2048*64 bf16  [p][t][c]

__device__ __forceinline__ unsigned short f2bf(float f) {
    unsigned int i = __float_as_uint(f);
    i += 0x7FFFu + ((i >> 16) & 1u);       // RNE
    return (unsigned short)(i >> 16);
}
__device__ __forceinline__ float bf2f(unsigned short u) {
    return __uint_as_float((unsigned)u << 16);
}
// pack 2 floats -> 2 bf16 in one u32 (round-half-up)
__device__ __forceinline__ unsigned pk2bf(float a, float b) {
    unsigned ua = __float_as_uint(a) + 0x8000u;
    unsigned ub = __float_as_uint(b) + 0x8000u;
    return __builtin_amdgcn_perm(ub, ua, 0x07060302u);
}
// XOR-swizzled Xl addressing: 260 rows x 8 cells x 8 bf16 (pad-free).
__device__ __forceinline__ int xidx(int tt, int ci) {
    return tt * 64 + (((ci ^ (tt & 7)) << 3));
}

// ---------------------------------------------------------------------------
// K0: blocks 0..143 pack conv weights into MFMA A-frag layout (bf16);
//     block 144 does Laplacian/Cheb/Weff prep + zeroes stats shards.
// ---------------------------------------------------------------------------
__global__ __launch_bounds__(TPB)
void prep_kernel(const float* __restrict__ adj, const float* __restrict__ theta,
                 const float* __restrict__ w1a,
                 const float* __restrict__ w1b, const float* __restrict__ w2a,
                 const float* __restrict__ w2b,
                 float* __restrict__ tk, float* __restrict__ weff,
                 unsigned short* __restrict__ wf, float* __restrict__ stats)
{
    const int tid = threadIdx.x;
    if (blockIdx.x < 144) {
        int e = blockIdx.x * TPB + tid;
        int conv = e / 12288, r = e % 12288;
        int oh = r / 6144; r %= 6144;
        int kc = r / 512;  r %= 512;
        int lane = r / 8;
        int jj = r % 8;
        int o = oh * 32 + (lane & 31);
        int K = kc * 16 + (lane >> 5) * 8 + jj;
        int j = K / 64, c2 = K % 64;
        const float* w = (conv == 0) ? w1b : ((conv == 1) ? w2a : w2b);
        wf[e] = f2bf(w[(o * 64 + c2) * 3 + j]);
        return;
    }

    __shared__ float disl[24];
    __shared__ float Ll[576];
    __shared__ float T2l[576];

    for (int e = tid; e < 4 * 8192; e += TPB) stats[e] = 0.f;

    if (tid < 24) {
        float d = 0.f;
        for (int j = 0; j < 24; ++j) d += adj[tid * 24 + j];
        disl[tid] = (d > 0.f) ? 1.0f / sqrtf(d) : 0.f;
    }
    __syncthreads();
    for (int e = tid; e < 576; e += TPB) {
        int i = e / 24, j = e % 24;
        Ll[e] = disl[i] * adj[j * 24 + i] * disl[j];
    }
    __syncthreads();
    for (int e = tid; e < 576; e += TPB) {
        int i = e / 24, j = e % 24;
        float a = 0.f;
        for (int m = 0; m < 24; ++m) a += Ll[i * 24 + m] * Ll[m * 24 + j];
        T2l[e] = 2.f * a - ((i == j) ? 1.f : 0.f);
    }
    __syncthreads();
    for (int e = tid; e < 576; e += TPB) {
        int i = e / 24, j = e % 24;
        tk[e]        = (i == j) ? 1.f : 0.f;
        tk[576 + e]  = Ll[e];
        tk[1152 + e] = T2l[e];
    }
    for (int e = tid; e < 576; e += TPB) {
        int o = e / 9, k = (e % 9) / 3, j = e % 3;
        float a = 0.f;
        for (int c2 = 0; c2 < 64; ++c2)
            a += w1a[(o * 64 + c2) * 3 + j] * theta[k * 64 + c2];
        weff[(k * 3 + j) * 64 + o] = a;
    }
}

// ---------------------------------------------------------------------------
// bnprep: parallel reduce one sharded-stats slot -> per-channel (a,b).
// ---------------------------------------------------------------------------
__global__ __launch_bounds__(TPB)
void bnprep_kernel(const float* __restrict__ stats, const float* __restrict__ g,
                   const float* __restrict__ be, float2* __restrict__ ab)
{
    const int tid = threadIdx.x;
    const int ch = tid >> 2, q = tid & 3;
    float s1 = 0.f, s2 = 0.f;
    #pragma unroll
    for (int u = 0; u < 16; ++u) {
        int sh = q * 16 + u;
        s1 += stats[ch * 64 + sh];
        s2 += stats[(64 + ch) * 64 + sh];
    }
    s1 += __shfl_xor(s1, 1); s1 += __shfl_xor(s1, 2);
    s2 += __shfl_xor(s2, 1); s2 += __shfl_xor(s2, 2);
    if (q == 0) {
        float mu  = s1 * INV_CNT;
        float var = s2 * INV_CNT - mu * mu;
        float a = g[ch] * (1.0f / sqrtf(var + 1e-5f));
        ab[ch] = make_float2(a, be[ch] - mu * a);
    }
}

// ---------------------------------------------------------------------------
// K1: s[k,p,t] = sum_m batch_x[b,t,m] * Tk[k,m,n]; grid over (b,k,tc)
// ---------------------------------------------------------------------------
__global__ __launch_bounds__(TPB)
void s_kernel(const float* __restrict__ bx, const float* __restrict__ tk,
              float* __restrict__ sbuf)
{
    __shared__ float bxs[256 * 25];
    __shared__ float tkl[576];
    const int tid = threadIdx.x;
    const int blk = blockIdx.x;
    const int b  = blk / 24;
    const int r  = blk % 24;
    const int k  = r >> 3;
    const int t0 = (r & 7) * 256;

    for (int e = tid; e < 576; e += TPB) tkl[e] = tk[k * 576 + e];
    for (int e = tid; e < 256 * 24; e += TPB) {
        int t = e / 24, m = e % 24;
        bxs[t * 25 + m] = bx[((long)b * TDIM + t0 + t) * NN + m];
    }
    __syncthreads();

    const int t = tid;
    float acc[24];
    #pragma unroll
    for (int n = 0; n < 24; ++n) acc[n] = 0.f;
    for (int m = 0; m < 24; ++m) {
        float xb = bxs[t * 25 + m];
        const float* tr = tkl + m * 24;
        #pragma unroll
        for (int n = 0; n < 24; ++n) acc[n] = fmaf(xb, tr[n], acc[n]);
    }
    for (int n = 0; n < 24; ++n)
        sbuf[((long)k * P + b * NN + n) * TDIM + t0 + t] = acc[n];
}

// ---------------------------------------------------------------------------
// K2: stats of y1a = Weff-conv(s) (bias-free; no store)
// ---------------------------------------------------------------------------
__global__ __launch_bounds__(TPB)
void stats1a_kernel(const float* __restrict__ sbuf, const float* __restrict__ weff,
                    float* __restrict__ statsOut)
{
    __shared__ float4 ssl4[3 * 66];
    __shared__ float4 wl4[144];
    __shared__ float  part[4][2][64];
    const int tid = threadIdx.x;
    const int blk = blockIdx.x;
    const int p  = blk >> 3;
    const int t0 = (blk & 7) * 256;

    for (int e = tid; e < 576; e += TPB) ((float*)wl4)[e] = weff[e];
    for (int e = tid; e < 3 * 65; e += TPB) {
        int k = e / 65, u4 = e % 65;
        int t = t0 - 4 + u4 * 4;
        float4 v = make_float4(0.f, 0.f, 0.f, 0.f);
        if (t >= 0) v = *(const float4*)(sbuf + ((long)k * P + p) * TDIM + t);
        ssl4[k * 66 + u4] = v;
    }
    __syncthreads();

    const int oq = tid & 7;
    const int tq = tid >> 3;
    float acc[8][8];
    #pragma unroll
    for (int i = 0; i < 8; ++i)
        #pragma unroll
        for (int ti = 0; ti < 8; ++ti) acc[i][ti] = 0.f;

    #pragma unroll
    for (int k = 0; k < 3; ++k) {
        float4 x0 = ssl4[k * 66 + tq * 2];
        float4 x1 = ssl4[k * 66 + tq * 2 + 1];
        float4 x2 = ssl4[k * 66 + tq * 2 + 2];
        float xv[12] = { x0.x,x0.y,x0.z,x0.w, x1.x,x1.y,x1.z,x1.w, x2.x,x2.y,x2.z,x2.w };
        #pragma unroll
        for (int j = 0; j < 3; ++j) {
            float4 w0 = wl4[(k * 3 + j) * 16 + oq * 2];
            float4 w1 = wl4[(k * 3 + j) * 16 + oq * 2 + 1];
            float wv[8] = { w0.x,w0.y,w0.z,w0.w, w1.x,w1.y,w1.z,w1.w };
            #pragma unroll
            for (int i = 0; i < 8; ++i)
                #pragma unroll
                for (int ti = 0; ti < 8; ++ti)
                    acc[i][ti] = fmaf(wv[i], xv[ti + 2 + j], acc[i][ti]);
        }
    }

    float s1v[8], s2v[8];
    #pragma unroll
    for (int i = 0; i < 8; ++i) {
        float a1 = 0.f, a2 = 0.f;
        #pragma unroll
        for (int ti = 0; ti < 8; ++ti) { a1 += acc[i][ti]; a2 += acc[i][ti] * acc[i][ti]; }
        s1v[i] = a1; s2v[i] = a2;
    }
    #pragma unroll
    for (int m = 8; m < 64; m <<= 1) {
        #pragma unroll
        for (int i = 0; i < 8; ++i) {
            s1v[i] += __shfl_xor(s1v[i], m);
            s2v[i] += __shfl_xor(s2v[i], m);
        }
    }
    const int wave = tid >> 6, lane = tid & 63;
    if (lane < 8) {
        #pragma unroll
        for (int i = 0; i < 8; ++i) {
            part[wave][0][oq * 8 + i] = s1v[i];
            part[wave][1][oq * 8 + i] = s2v[i];
        }
    }
    __syncthreads();
    if (tid < 128) {
        int s = tid >> 6, o = tid & 63;
        float tot = part[0][s][o] + part[1][s][o] + part[2][s][o] + part[3][s][o];
        atomicAdd(&statsOut[(s * 64 + o) * NSHARD + (blk & 63)], tot);
    }
}

// ---------------------------------------------------------------------------
// MFMA conv pass — R10 structure (swizzled Xl, scratch overlay, 4 blocks/CU)
// with ONLY the R11 register-hoist added: per-thread BN (a,b) and theta
// coefficients live in registers (cb = tid&7 is constant), killing the
// 4-way-conflicted abl/thl LDS reads in the staging loop.
// MODE 0: conv1b — xin from s (Weff conv + BN1a + relu), dil 1.
// MODE 1: conv2a — xin = relu(relu(BN1b(yin)) + gc), dil 2; fp32 out0 tail.
// MODE 2: conv2b — xin = relu(BN2a(yin)), dil 2; fp32 last-25 tail only;
//         stats straight from accumulators, no epilogue.
// ---------------------------------------------------------------------------
template<int MODE>
__global__ __launch_bounds__(TPB, 4)
void conv_mfma(const float* __restrict__ sbuf, const unsigned short* __restrict__ yin,
               unsigned short* __restrict__ yout, float* __restrict__ ytail,
               const unsigned short* __restrict__ wf, const float* __restrict__ weff,
               const float2* __restrict__ bnab, float* __restrict__ statsOut,
               const float* __restrict__ theta, float* __restrict__ o0s)
{
    constexpr int SCR = (MODE == 0) ? (792 + 576) : ((MODE == 1) ? (792 + 192) : 512);
    __shared__ unsigned short Xl[260 * 64];   // 33.25 KB, XOR-swizzled cells
    __shared__ float  scratch[SCR];           // staging: ssl(+weffl/thl); end: parts
    __shared__ float2 abl[64];

    float* const ssl   = scratch;             // [3][264] (MODE<=1), staging only
    float* const weffl = scratch + 792;       // MODE 0
    float* const thl   = scratch + 792;       // MODE 1
    float* const parts = scratch;             // reused after staging completes

    const int tid  = threadIdx.x;
    const int lane = tid & 63;
    const int w    = tid >> 6;
    const int oh   = w & 1;
    const int l31  = lane & 31;
    const int h    = lane >> 5;
    const int cb   = tid & 7;                 // channel-block, constant/thread
    const int blk  = blockIdx.x;
    const int p    = blk >> 3;
    const int tile = blk & 7;
    const int t0   = tile * TILE;

    // A-fragments (weights), resident
    short8 af[12];
    #pragma unroll
    for (int kc = 0; kc < 12; ++kc)
        af[kc] = *((const short8*)wf + (oh * 12 + kc) * 64 + lane);

    if (tid < 64) abl[tid] = bnab[tid];       // precomputed BN (a,b)
    if (MODE == 0)
        for (int e = tid; e < 576; e += TPB) weffl[e] = weff[e];
    if (MODE == 1)
        if (tid < 192) thl[tid] = theta[tid];
    if (MODE <= 1) {
        // s halo 8: ssl[k][it] = s[k][t0-8+it], it in 0..263
        for (int e = tid; e < 3 * 66; e += TPB) {
            int k = e / 66, u4 = e % 66;
            int t = t0 - 8 + u4 * 4;
            float4 v = make_float4(0.f, 0.f, 0.f, 0.f);
            if (t >= 0) v = *(const float4*)(sbuf + ((long)k * P + p) * TDIM + t);
            *(float4*)(ssl + k * 264 + u4 * 4) = v;
        }
    }
    __syncthreads();

    // register-hoisted per-thread coefficients (cb fixed -> 8 channels)
    float2 ab2[8];
    #pragma unroll
    for (int r = 0; r < 8; ++r) ab2[r] = abl[cb * 8 + r];
    float th2[3][8];
    if (MODE == 1) {
        #pragma unroll
        for (int k = 0; k < 3; ++k)
            #pragma unroll
            for (int r = 0; r < 8; ++r) th2[k][r] = thl[k * 64 + cb * 8 + r];
    }

    // ---- stage X transposed [t][c] (swizzled): tasks (tt 0..259, cb fixed)
    const unsigned short* yinb = (MODE >= 1)
        ? (yin + ((long)p * TDIM + t0 - 4) * 64) : nullptr;
    for (int e = tid; e < 260 * 8; e += TPB) {
        const int tt = e >> 3;
        const int t = t0 - 4 + tt;
        float xv[8];
        if (t < 0) {
            #pragma unroll
            for (int r = 0; r < 8; ++r) xv[r] = 0.f;   // causal zero pad
        } else if (MODE == 0) {
            float sv[9];
            #pragma unroll
            for (int k = 0; k < 3; ++k)
                #pragma unroll
                for (int j = 0; j < 3; ++j)
                    sv[k * 3 + j] = ssl[k * 264 + tt + 2 + j];
            #pragma unroll
            for (int r = 0; r < 8; ++r) {
                int c = cb * 8 + r;
                float raw = 0.f;
                #pragma unroll
                for (int u = 0; u < 9; ++u)
                    raw = fmaf(weffl[u * 64 + c], sv[u], raw);
                xv[r] = fmaxf(fmaf(ab2[r].x, raw, ab2[r].y), 0.f);
            }
        } else {
            short8 yv8 = *(const short8*)(yinb + (long)e * 8);
            float gcb[3];
            if (MODE == 1) {
                gcb[0] = ssl[      tt + 4];
                gcb[1] = ssl[264 + tt + 4];
                gcb[2] = ssl[528 + tt + 4];
            }
            #pragma unroll
            for (int r = 0; r < 8; ++r) {
                float v = bf2f((unsigned short)yv8[r]);
                float hh = fmaxf(fmaf(ab2[r].x, v, ab2[r].y), 0.f);
                if (MODE == 1) {
                    float gc = th2[0][r] * gcb[0] + th2[1][r] * gcb[1] + th2[2][r] * gcb[2];
                    hh = fmaxf(hh + gc, 0.f);
                }
                xv[r] = hh;
            }
        }
        if (MODE == 1 && tile == 7 && tt >= 235) {
            #pragma unroll
            for (int r = 0; r < 8; ++r)
                o0s[(long)p * 1600 + (cb * 8 + r) * 25 + (tt - 235)] = xv[r];
        }
        uint4 pk;
        pk.x = pk2bf(xv[0], xv[1]);
        pk.y = pk2bf(xv[2], xv[3]);
        pk.z = pk2bf(xv[4], xv[5]);
        pk.w = pk2bf(xv[6], xv[7]);
        *(uint4*)(Xl + xidx(tt, cb)) = pk;
    }
    __syncthreads();

    // ---- MFMA: wave w -> o-half oh, t-tiles (w>>1)*4 .. +3
    float16 acc[4];
    #pragma unroll
    for (int i = 0; i < 4; ++i)
        #pragma unroll
        for (int r = 0; r < 16; ++r) acc[i][r] = 0.f;

    const int tqb = (w >> 1) * 4;
    #pragma unroll
    for (int kc = 0; kc < 12; ++kc) {
        const int j = kc >> 2;
        const int roff = (MODE == 0) ? (2 + j) : (2 * j);   // dil 1 / dil 2
        const int ci = (kc & 3) * 2 + h;                    // 16-B cell index
        #pragma unroll
        for (int i = 0; i < 4; ++i) {
            int row = (tqb + i) * 32 + l31 + roff;
            short8 bfr = *(const short8*)(Xl + xidx(row, ci));
            acc[i] = __builtin_amdgcn_mfma_f32_32x32x16_bf16(af[kc], bfr, acc[i], 0, 0, 0);
        }
    }

    if (MODE <= 1) {
        __syncthreads();   // all B-frag reads of Xl done (ssl also dead now)

        // ---- epilogue: acc -> Xl (bf16, [t][c], swizzled)
        #pragma unroll
        for (int i = 0; i < 4; ++i) {
            int tl = (tqb + i) * 32 + l31;
            #pragma unroll
            for (int qq = 0; qq < 4; ++qq) {
                int ci = oh * 4 + qq;                       // cell; 4h = half-cell
                uint2 pk;
                pk.x = pk2bf(acc[i][4 * qq + 0], acc[i][4 * qq + 1]);
                pk.y = pk2bf(acc[i][4 * qq + 2], acc[i][4 * qq + 3]);
                *(uint2*)(Xl + xidx(tl, ci) + 4 * h) = pk;
            }
        }
        __syncthreads();

        // ---- coalesced global store + stats from the bf16 tile
        unsigned short* youtb = yout + ((long)p * TDIM + t0) * 64;
        float s1[8], s2[8];
        #pragma unroll
        for (int r = 0; r < 8; ++r) { s1[r] = 0.f; s2[r] = 0.f; }
        for (int e = tid; e < 2048; e += TPB) {
            int tt = e >> 3;
            uint4 v = *(const uint4*)(Xl + xidx(tt, cb));
            *(uint4*)(youtb + (long)e * 8) = v;
            unsigned uu[4] = { v.x, v.y, v.z, v.w };
            #pragma unroll
            for (int qq = 0; qq < 4; ++qq) {
                float f0 = __uint_as_float(uu[qq] << 16);
                float f1 = __uint_as_float(uu[qq] & 0xFFFF0000u);
                s1[2 * qq]     += f0;  s2[2 * qq]     = fmaf(f0, f0, s2[2 * qq]);
                s1[2 * qq + 1] += f1;  s2[2 * qq + 1] = fmaf(f1, f1, s2[2 * qq + 1]);
            }
        }
        #pragma unroll
        for (int m = 8; m <= 32; m <<= 1) {
            #pragma unroll
            for (int r = 0; r < 8; ++r) {
                s1[r] += __shfl_xor(s1[r], m);
                s2[r] += __shfl_xor(s2[r], m);
            }
        }
        if (lane < 8) {
            float* pw = parts + (w * 8 + lane) * 16;        // max idx 511 < SCR ok
            #pragma unroll
            for (int r = 0; r < 8; ++r) { pw[r * 2] = s1[r]; pw[r * 2 + 1] = s2[r]; }
        }
        __syncthreads();
        if (tid < 64) {
            int o = tid, cbo = o >> 3, r = o & 7;
            float t1 = 0.f, t2 = 0.f;
            #pragma unroll
            for (int ww = 0; ww < 4; ++ww) {
                t1 += parts[(ww * 8 + cbo) * 16 + r * 2];
                t2 += parts[(ww * 8 + cbo) * 16 + r * 2 + 1];
            }
            atomicAdd(&statsOut[o * NSHARD + (blk & 63)], t1);
            atomicAdd(&statsOut[(64 + o) * NSHARD + (blk & 63)], t2);
        }
    } else {
        // ---- MODE 2: fp32 tail store + stats straight from accumulators
        if (tile == 7) {
            #pragma unroll
            for (int i = 0; i < 4; ++i) {
                int tg = t0 + (tqb + i) * 32 + l31;
                if (tg >= TDIM - 25) {
                    #pragma unroll
                    for (int r = 0; r < 16; ++r) {
                        int o = oh * 32 + (r & 3) + 8 * (r >> 2) + 4 * h;
                        ytail[((long)p * C + o) * 25 + (tg - (TDIM - 25))] = acc[i][r];
                    }
                }
            }
        }
        float s1[16], s2[16];
        #pragma unroll
        for (int r = 0; r < 16; ++r) {
            float a1 = 0.f, a2 = 0.f;
            #pragma unroll
            for (int i = 0; i < 4; ++i) { float v = acc[i][r]; a1 += v; a2 = fmaf(v, v, a2); }
            s1[r] = a1; s2[r] = a2;
        }
        #pragma unroll
        for (int m = 1; m <= 16; m <<= 1) {
            #pragma unroll
            for (int r = 0; r < 16; ++r) {
                s1[r] += __shfl_xor(s1[r], m);
                s2[r] += __shfl_xor(s2[r], m);
            }
        }
        if (l31 == 0) {
            float* pw = parts + (w * 2 + h) * 32;           // max idx 255 < 512 ok
            #pragma unroll
            for (int r = 0; r < 16; ++r) { pw[r * 2] = s1[r]; pw[r * 2 + 1] = s2[r]; }
        }
        __syncthreads();
        if (tid < 64) {
            int o = tid;
            int ohh = o >> 5, v = o & 31;
            int hh = (v >> 2) & 1, r = (v & 3) + 4 * (v >> 3);
            float t1 = parts[(ohh * 2 + hh) * 32 + r * 2]
                     + parts[((ohh + 2) * 2 + hh) * 32 + r * 2];
            float t2 = parts[(ohh * 2 + hh) * 32 + r * 2 + 1]
                     + parts[((ohh + 2) * 2 + hh) * 32 + r * 2 + 1];
            atomicAdd(&statsOut[o * NSHARD + (blk & 63)], t1);
            atomicAdd(&statsOut[(64 + o) * NSHARD + (blk & 63)], t2);
        }
    }
}

// ---------------------------------------------------------------------------
// K6: head. out = relu(bn2b(ytail)) + out0 ; 1x1 conv -> relu ; (1,2) conv ;
//     slice last 24 t ; transpose -> d_out[b, tau, n]
// ---------------------------------------------------------------------------
__global__ __launch_bounds__(TPB)
void end_kernel(const float* __restrict__ ytail, const float* __restrict__ o0s,
                const float2* __restrict__ bnab, const float* __restrict__ w_end,
                const float* __restrict__ b_end, const float* __restrict__ w_end1,
                const float* __restrict__ b_end1, float* __restrict__ out)
{
    __shared__ float2 abl[64];
    __shared__ float outl[64 * 25];
    __shared__ float e1l[32 * 25];
    __shared__ float wendl[2048];
    const int tid = threadIdx.x;
    const int p = blockIdx.x;
    const int b = p / 24, n = p % 24;

    if (tid < 64) abl[tid] = bnab[tid];
    for (int e = tid; e < 2048; e += TPB) wendl[e] = w_end[e];
    __syncthreads();

    for (int e = tid; e < 1600; e += TPB) {
        int c = e / 25, tau = e % 25;
        float v = ytail[((long)p * C + c) * 25 + tau];
        float2 ab = abl[c];
        outl[e] = fmaxf(ab.x * v + ab.y, 0.f) + o0s[(long)p * 1600 + e];
    }
    __syncthreads();
    for (int e = tid; e < 800; e += TPB) {
        int q = e / 25, tau = e % 25;
        float a = b_end[q];
        for (int c = 0; c < 64; ++c)
            a = fmaf(wendl[q * 64 + c], outl[c * 25 + tau], a);
        e1l[e] = fmaxf(a, 0.f);
    }
    __syncthreads();
    if (tid < 24) {
        float a = b_end1[0];
        #pragma unroll
        for (int q = 0; q < 32; ++q)
            a += w_end1[q * 2] * e1l[q * 25 + tid] + w_end1[q * 2 + 1] * e1l[q * 25 + tid + 1];
        out[((long)b * 24 + tid) * 24 + n] = a;
    }
}

// ---------------------------------------------------------------------------
extern "C" void kernel_launch(void* const* d_in, const int* in_sizes, int n_in,
                              void* d_out, int out_size, void* d_ws, size_t ws_size,
                              hipStream_t stream)
{
    (void)in_sizes; (void)n_in; (void)out_size; (void)ws_size;
    const float* bx    = (const float*)d_in[0];
    const float* adj   = (const float*)d_in[1];
    const float* theta = (const float*)d_in[2];
    const float* w1a   = (const float*)d_in[3];
    const float* g1a   = (const float*)d_in[5];
    const float* be1a  = (const float*)d_in[6];
    const float* w1b   = (const float*)d_in[7];
    const float* g1b   = (const float*)d_in[9];
    const float* be1b  = (const float*)d_in[10];
    const float* w2a   = (const float*)d_in[11];
    const float* g2a   = (const float*)d_in[13];
    const float* be2a  = (const float*)d_in[14];
    const float* w2b   = (const float*)d_in[15];
    const float* g2b   = (const float*)d_in[17];
    const float* be2b  = (const float*)d_in[18];
    const float* wend  = (const float*)d_in[19];
    const float* bend  = (const float*)d_in[20];
    const float* wend1 = (const float*)d_in[21];
    const float* bend1 = (const float*)d_in[22];

    char* ws = (char*)d_ws;
    float*          tk    = (float*)(ws + OFF_TK);
    float*          weff  = (float*)(ws + OFF_WEFF);
    unsigned short* wf    = (unsigned short*)(ws + OFF_WFRAG);
    float*          stats = (float*)(ws + OFF_ST);
    float2*         bnab  = (float2*)(ws + OFF_BNAB);
    float*          o0s   = (float*)(ws + OFF_O0);
    float*          ytail = (float*)(ws + OFF_YT);
    float*          sb    = (float*)(ws + OFF_S);
    unsigned short* yA    = (unsigned short*)(ws + OFF_YA);
    unsigned short* yB    = (unsigned short*)(ws + OFF_YB);

    prep_kernel   <<<145, TPB, 0, stream>>>(adj, theta, w1a, w1b, w2a, w2b,
                                            tk, weff, wf, stats);
    s_kernel      <<<384, TPB, 0, stream>>>(bx, tk, sb);
    stats1a_kernel<<<P * NBT, TPB, 0, stream>>>(sb, weff, stats);
    bnprep_kernel <<<1, TPB, 0, stream>>>(stats,         g1a, be1a, bnab);

    // conv1b: s -> yA, BN1a consumer-side, stats -> slot1
    conv_mfma<0><<<P * NBT, TPB, 0, stream>>>(
        sb, nullptr, yA, nullptr, wf, weff,
        bnab, stats + 8192, nullptr, nullptr);
    bnprep_kernel <<<1, TPB, 0, stream>>>(stats + 8192,  g1b, be1b, bnab + 64);

    // conv2a: yA -> yB, BN1b + gc residual, stats -> slot2, fp32 out0 tail
    conv_mfma<1><<<P * NBT, TPB, 0, stream>>>(
        sb, yA, yB, nullptr, wf + 12288, nullptr,
        bnab + 64, stats + 16384, theta, o0s);
    bnprep_kernel <<<1, TPB, 0, stream>>>(stats + 16384, g2a, be2a, bnab + 128);

    // conv2b: yB -> ytail (fp32 last-25), BN2a, stats -> slot3
    conv_mfma<2><<<P * NBT, TPB, 0, stream>>>(
        sb, yB, nullptr, ytail, wf + 24576, nullptr,
        bnab + 128, stats + 24576, nullptr, nullptr);
    bnprep_kernel <<<1, TPB, 0, stream>>>(stats + 24576, g2b, be2b, bnab + 192);

    end_kernel<<<P, TPB, 0, stream>>>(ytail, o0s, bnab + 192,
                                      wend, bend, wend1, bend1, (float*)d_out);
}